// Round 8
// baseline (778.354 us; speedup 1.0000x reference)
//
#include <hip/hip_runtime.h>

typedef unsigned short u16;
typedef __attribute__((ext_vector_type(8))) short short8;   // 8 bf16 (4 VGPRs)
typedef __attribute__((ext_vector_type(4))) float f32x4;    // MFMA acc

static constexpr int Bn  = 4;
static constexpr int C   = 512;
static constexpr int HW  = 4096;
static constexpr int HID = 256;

__device__ __forceinline__ float bf2f(u16 u){
  union { unsigned int i; float f; } x; x.i = ((unsigned int)u) << 16; return x.f;
}
__device__ __forceinline__ u16 f2bf(float f){
  union { float f; unsigned int i; } x; x.f = f;
  return (u16)((x.i + 0x7fffu + ((x.i >> 16) & 1u)) >> 16);
}
__device__ __forceinline__ float wsum(float v){
  #pragma unroll
  for (int o = 32; o > 0; o >>= 1) v += __shfl_xor(v, o, 64);
  return v;
}
__device__ __forceinline__ float wmax(float v){
  #pragma unroll
  for (int o = 32; o > 0; o >>= 1) v = fmaxf(v, __shfl_xor(v, o, 64));
  return v;
}
__device__ __forceinline__ uint4 pk8(u16 a,u16 b,u16 c,u16 d,u16 e,u16 f,u16 g,u16 h){
  uint4 r; r.x=(unsigned)a|((unsigned)b<<16); r.y=(unsigned)c|((unsigned)d<<16);
  r.z=(unsigned)e|((unsigned)f<<16); r.w=(unsigned)g|((unsigned)h<<16); return r;
}
// NOTE (R5 post-mortem): XCD "contiguous chunk" swizzle REGRESSED (FETCH
// 86->261 MB). Default round-robin dispatch already gives each XCD an
// L2-fitting A+B panel scatter. Identity mapping kept.
// async global->LDS DMA, 16B per lane; lds dest = wave-uniform base + lane*16
__device__ __forceinline__ void gld16(const u16* g, u16* l){
  __builtin_amdgcn_global_load_lds((const __attribute__((address_space(1))) void*)g,
                                   (__attribute__((address_space(3))) void*)l, 16, 0, 0);
}

// ---------------- MFMA core: 128x128 block tile, 4 waves, DMA-staged --------
// A: M x K row-major bf16 (pitch pA), B: N x K row-major bf16 (pitch pB) -> NT
// BK=32, counted vmcnt (never 0 in-loop).
// XOR bank-swizzle (both-sides, rule #21): read chunk = kq ^ ((fr>>1)&3);
// global source pre-permuted per lane: (l&3)^((l>>3)&3). Measured: bank
// conflicts 4.19M -> 0, MfmaUtil 28 -> 39% (R4).
// SPLIT=true: 2-buffer 1-deep (64 KB LDS keeps 2 blocks/CU); 3 passes
// (hh, h*l, l*h) for ~fp32 accuracy.
// SPLIT=false: 3-buffer 2-DEEP prefetch (48 KB, still 3 blocks/CU) -- plain
// kernels often run at 1 block/CU grids (256); doubled in-flight staging
// covers memory latency that single-deep exposed. Requires K >= 96 (all
// plain uses have K/Kper in {256,512,1024,2048,4096}).
template<bool SPLIT>
__device__ __forceinline__ void mfma_core(const u16* __restrict__ Ah, const u16* __restrict__ Al, int pA,
                                          const u16* __restrict__ Bh, const u16* __restrict__ Bl, int pB,
                                          int K, u16* lds, f32x4 (&acc)[4][4]){
  const int tid  = threadIdx.x;
  const int lane = tid & 63, wave = tid >> 6;
  const int fr = lane & 15, kq = lane >> 4;      // frag row / k-quad
  const int kqs = (kq ^ ((fr >> 1) & 3)) * 8;    // swizzled k-chunk (u16 idx)
  const int wm = (wave & 1) * 64, wn = (wave >> 1) * 64;
  constexpr int HB = SPLIT ? 16384 : 8192;       // u16 per buffer (32/16 KB)
  const int srow = wave*32 + (lane >> 2);        // staging row (+i*16), i in {0,1}
  const int sq   = (((lane & 3) ^ ((lane >> 3) & 3))) * 8;  // inverse-swz src k
  const size_t ga = (size_t)srow * pA + sq;
  const size_t gb = (size_t)srow * pB + sq;
  const int ldsc = wave * 1024;                  // wave chunk base (u16 idx)

  auto stage = [&](int buf, int k0){
    u16* L = lds + buf*HB;
    #pragma unroll
    for (int i = 0; i < 2; ++i){
      gld16(Ah + ga + (size_t)i*16*pA + k0, L + ldsc + i*512);
      gld16(Bh + gb + (size_t)i*16*pB + k0, L + 4096 + ldsc + i*512);
      if constexpr (SPLIT){
        gld16(Al + ga + (size_t)i*16*pA + k0, L + 8192  + ldsc + i*512);
        gld16(Bl + gb + (size_t)i*16*pB + k0, L + 12288 + ldsc + i*512);
      }
    }
  };
  auto compute = [&](int buf){
    u16* L = lds + buf*HB;
    short8 a[4], b[4];
    #pragma unroll
    for (int i = 0; i < 4; ++i){
      a[i] = *(const short8*)&L[(wm + i*16 + fr)*32 + kqs];
      b[i] = *(const short8*)&L[4096 + (wn + i*16 + fr)*32 + kqs];
    }
    #pragma unroll
    for (int i = 0; i < 4; ++i)
      #pragma unroll
      for (int j = 0; j < 4; ++j)
        acc[i][j] = __builtin_amdgcn_mfma_f32_16x16x32_bf16(a[i], b[j], acc[i][j], 0, 0, 0);
    if constexpr (SPLIT){
      short8 a2[4], b2[4];
      #pragma unroll
      for (int i = 0; i < 4; ++i){
        a2[i] = *(const short8*)&L[8192  + (wm + i*16 + fr)*32 + kqs];
        b2[i] = *(const short8*)&L[12288 + (wn + i*16 + fr)*32 + kqs];
      }
      #pragma unroll
      for (int i = 0; i < 4; ++i)
        #pragma unroll
        for (int j = 0; j < 4; ++j){
          acc[i][j] = __builtin_amdgcn_mfma_f32_16x16x32_bf16(a[i],  b2[j], acc[i][j], 0, 0, 0);
          acc[i][j] = __builtin_amdgcn_mfma_f32_16x16x32_bf16(a2[i], b[j],  acc[i][j], 0, 0, 0);
        }
    }
  };

  if constexpr (SPLIT){
    // ---- 2-buffer, 1-deep (proven R4) ----
    stage(0, 0);
    int cur = 0;
    for (int k0 = 32; k0 < K; k0 += 32){
      stage(cur ^ 1, k0);                       // prefetch next K-step
      asm volatile("s_waitcnt vmcnt(8)" ::: "memory");
      __builtin_amdgcn_s_barrier();             // cur-buffer DMA landed (all waves)
      compute(cur);
      __builtin_amdgcn_s_barrier();             // reads done before next overwrite
      cur ^= 1;
    }
    asm volatile("s_waitcnt vmcnt(0)" ::: "memory");
    __builtin_amdgcn_s_barrier();
    compute(cur);
  } else {
    // ---- 3-buffer, 2-deep: stage k+2 while computing k ----
    // main loop: 3 stages (12 instrs) outstanding; vmcnt(8) -> oldest landed.
    // Overwrite hazard: stage into (cur+2)%3 == (cur-1)%3, whose readers all
    // passed the trailing barrier of the previous iteration.
    stage(0, 0); stage(1, 32);
    int cur = 0;
    for (int k0 = 64; k0 < K; k0 += 32){
      stage(cur == 0 ? 2 : cur - 1, k0);
      asm volatile("s_waitcnt vmcnt(8)" ::: "memory");
      __builtin_amdgcn_s_barrier();
      compute(cur);
      __builtin_amdgcn_s_barrier();
      cur = (cur == 2) ? 0 : cur + 1;
    }
    asm volatile("s_waitcnt vmcnt(4)" ::: "memory");
    __builtin_amdgcn_s_barrier();
    compute(cur);
    __builtin_amdgcn_s_barrier();
    cur = (cur == 2) ? 0 : cur + 1;
    asm volatile("s_waitcnt vmcnt(0)" ::: "memory");
    __builtin_amdgcn_s_barrier();
    compute(cur);
  }
}

struct TileCtx { int wm, wn, cn, rq; };
__device__ __forceinline__ TileCtx tctx(int bx, int by){
  TileCtx t;
  const int wave = threadIdx.x >> 6, lane = threadIdx.x & 63;
  t.wm = by * 128 + (wave & 1) * 64;
  t.wn = bx * 128 + (wave >> 1) * 64;
  t.cn = lane & 15; t.rq = (lane >> 4) * 4;
  return t;
}
#define ACC_ZERO(acc) { _Pragma("unroll") for (int i=0;i<4;++i) _Pragma("unroll") for (int j=0;j<4;++j) _Pragma("unroll") for (int r=0;r<4;++r) acc[i][j][r]=0.f; }

// merged Fq/Gk conv: blockIdx.z = b*2 + z (z=0: content->Fq, z=1: style->Gk)
__global__ __launch_bounds__(256) void g_conv_split2(const u16* __restrict__ A0h, const u16* __restrict__ A0l,
                                                     const u16* __restrict__ A1h, const u16* __restrict__ A1l,
                                                     const u16* __restrict__ B0h, const u16* __restrict__ B0l,
                                                     const u16* __restrict__ B1h, const u16* __restrict__ B1l,
                                                     const float* __restrict__ bias0, const float* __restrict__ bias1,
                                                     u16* __restrict__ O0h, u16* __restrict__ O0l,
                                                     u16* __restrict__ O1h, u16* __restrict__ O1l,
                                                     size_t bsA, size_t bsO){
  __shared__ u16 lds[32768];   // 64 KB: 2 x (Ah,Bh,Al,Bl)
  const int zb = blockIdx.z, b = zb >> 1, z = zb & 1;
  const u16* Ah = (z ? A1h : A0h) + (size_t)b*bsA;  const u16* Al = (z ? A1l : A0l) + (size_t)b*bsA;
  const u16* Bh = z ? B1h : B0h;  const u16* Bl = z ? B1l : B0l;   // weights, shared
  const float* bias = z ? bias1 : bias0;
  u16* Ohi = (z ? O1h : O0h) + (size_t)b*bsO;  u16* Olo = (z ? O1l : O0l) + (size_t)b*bsO;
  TileCtx t = tctx(blockIdx.x, blockIdx.y);
  f32x4 acc[4][4]; ACC_ZERO(acc);
  mfma_core<true>(Ah + (size_t)blockIdx.y*128*C, Al + (size_t)blockIdx.y*128*C, C,
                  Bh + (size_t)blockIdx.x*128*C, Bl + (size_t)blockIdx.x*128*C, C, C, lds, acc);
  #pragma unroll
  for (int fm = 0; fm < 4; ++fm)
    #pragma unroll
    for (int fn = 0; fn < 4; ++fn)
      #pragma unroll
      for (int r = 0; r < 4; ++r){
        int gm = t.wm + fm*16 + t.rq + r;
        int gn = t.wn + fn*16 + t.cn;
        float v = acc[fm][fn][r] + bias[gn];
        u16 h = f2bf(v);
        Ohi[(size_t)gm*C + gn] = h;
        Olo[(size_t)gm*C + gn] = f2bf(v - bf2f(h));
      }
}

// split GEMM -> fp32 out (score logits T2); blockIdx.z = batch
__global__ __launch_bounds__(256) void g_gemm_split_f32(const u16* __restrict__ Ah, const u16* __restrict__ Al, int pA,
                                                        const u16* __restrict__ Bh, const u16* __restrict__ Bl, int pB,
                                                        int K, float* __restrict__ O, int pO,
                                                        size_t bsA, size_t bsB, size_t bsO){
  __shared__ u16 lds[32768];
  const int b = blockIdx.z;
  TileCtx t = tctx(blockIdx.x, blockIdx.y);
  f32x4 acc[4][4]; ACC_ZERO(acc);
  mfma_core<true>(Ah + (size_t)b*bsA + (size_t)blockIdx.y*128*pA,
                  Al + (size_t)b*bsA + (size_t)blockIdx.y*128*pA, pA,
                  Bh + (size_t)b*bsB + (size_t)blockIdx.x*128*pB,
                  Bl + (size_t)b*bsB + (size_t)blockIdx.x*128*pB, pB, K, lds, acc);
  float* Ob = O + (size_t)b*bsO;
  #pragma unroll
  for (int fm = 0; fm < 4; ++fm)
    #pragma unroll
    for (int fn = 0; fn < 4; ++fn)
      #pragma unroll
      for (int r = 0; r < 4; ++r)
        Ob[(size_t)(t.wm + fm*16 + t.rq + r)*pO + t.wn + fn*16 + t.cn] = acc[fm][fn][r];
}

// plain GEMM + bias[m] -> bf16 out (Hv conv); A (weights) shared, z = batch
__global__ __launch_bounds__(256) void g_gemm_biasm_bf16(const u16* __restrict__ A, int pA,
                                                         const u16* __restrict__ B, int pB,
                                                         int K, const float* __restrict__ bias,
                                                         u16* __restrict__ O, int pO,
                                                         size_t bsB, size_t bsO){
  __shared__ u16 lds[24576];   // 48 KB: 3 buffers
  const int b = blockIdx.z;
  TileCtx t = tctx(blockIdx.x, blockIdx.y);
  f32x4 acc[4][4]; ACC_ZERO(acc);
  mfma_core<false>(A + (size_t)blockIdx.y*128*pA, nullptr, pA,
                   B + (size_t)b*bsB + (size_t)blockIdx.x*128*pB, nullptr, pB, K, lds, acc);
  u16* Ob = O + (size_t)b*bsO;
  #pragma unroll
  for (int fm = 0; fm < 4; ++fm)
    #pragma unroll
    for (int fn = 0; fn < 4; ++fn)
      #pragma unroll
      for (int r = 0; r < 4; ++r){
        int gm = t.wm + fm*16 + t.rq + r;
        Ob[(size_t)gm*pO + t.wn + fn*16 + t.cn] = f2bf(acc[fm][fn][r] + bias[gm]);
      }
}

// plain GEMM -> bf16 out, no bias; z = batch
__global__ __launch_bounds__(256) void g_gemm_plain_bf16(const u16* __restrict__ A, int pA,
                                                         const u16* __restrict__ B, int pB,
                                                         int K, u16* __restrict__ O, int pO,
                                                         size_t bsA, size_t bsB, size_t bsO){
  __shared__ u16 lds[24576];
  const int b = blockIdx.z;
  TileCtx t = tctx(blockIdx.x, blockIdx.y);
  f32x4 acc[4][4]; ACC_ZERO(acc);
  mfma_core<false>(A + (size_t)b*bsA + (size_t)blockIdx.y*128*pA, nullptr, pA,
                   B + (size_t)b*bsB + (size_t)blockIdx.x*128*pB, nullptr, pB, K, lds, acc);
  u16* Ob = O + (size_t)b*bsO;
  #pragma unroll
  for (int fm = 0; fm < 4; ++fm)
    #pragma unroll
    for (int fn = 0; fn < 4; ++fn)
      #pragma unroll
      for (int r = 0; r < 4; ++r){
        int gm = t.wm + fm*16 + t.rq + r;
        Ob[(size_t)gm*pO + t.wn + fn*16 + t.cn] = f2bf(acc[fm][fn][r]);
      }
}

// split-K GEMM -> fp32 partials; blockIdx.z = b*slices + slice.
// Output addressing is fully parameterized (base/pO/sliceStride/bsO) so
// partials can live in "holey" regions (e.g. T2 dead row-halves).
__global__ __launch_bounds__(256) void g_gemm_partial(const u16* __restrict__ A, int pA,
                                                      const u16* __restrict__ B, int pB,
                                                      int Kper, float* __restrict__ O, int pO,
                                                      size_t sliceStride, int slices,
                                                      size_t bsA, size_t bsB, size_t bsO){
  __shared__ u16 lds[24576];
  const int zz = blockIdx.z;
  const int b = zz / slices, sl = zz - b*slices;
  TileCtx t = tctx(blockIdx.x, blockIdx.y);
  const int koff = sl * Kper;
  f32x4 acc[4][4]; ACC_ZERO(acc);
  mfma_core<false>(A + (size_t)b*bsA + (size_t)blockIdx.y*128*pA + koff, nullptr, pA,
                   B + (size_t)b*bsB + (size_t)blockIdx.x*128*pB + koff, nullptr, pB, Kper, lds, acc);
  float* Oz = O + (size_t)b*bsO + (size_t)sl * sliceStride;
  #pragma unroll
  for (int fm = 0; fm < 4; ++fm)
    #pragma unroll
    for (int fn = 0; fn < 4; ++fn)
      #pragma unroll
      for (int r = 0; r < 4; ++r)
        Oz[(size_t)(t.wm + fm*16 + t.rq + r)*pO + t.wn + fn*16 + t.cn] = acc[fm][fn][r];
}

// reduce S fp32 partials -> bf16 (4 elems/thread); blockIdx.y = batch
__global__ __launch_bounds__(256) void k_reduce(const float* __restrict__ in, size_t sliceStride,
                                                int S, u16* __restrict__ out,
                                                size_t bsIn, size_t bsOut){
  const int b = blockIdx.y;
  const float* inb = in + (size_t)b*bsIn;
  u16* outb = out + (size_t)b*bsOut;
  const size_t i4 = ((size_t)blockIdx.x*256 + threadIdx.x) * 4;
  float4 s = *(const float4*)&inb[i4];
  for (int z = 1; z < S; ++z){
    float4 v = *(const float4*)&inb[(size_t)z*sliceStride + i4];
    s.x += v.x; s.y += v.y; s.z += v.z; s.w += v.w;
  }
  u16 r0 = f2bf(s.x), r1 = f2bf(s.y), r2 = f2bf(s.z), r3 = f2bf(s.w);
  uint2 uo; uo.x = (unsigned)r0 | ((unsigned)r1 << 16);
  uo.y = (unsigned)r2 | ((unsigned)r3 << 16);
  *(uint2*)&outb[i4] = uo;
}

// reduce ogemm partials living in T2 dead row-halves: row k of batch b holds
// slices at in[b*bsIn + k*HW + {0,512} + c] (c<512); out bf16 [k][c] pitch C.
__global__ __launch_bounds__(256) void k_reduce2(const float* __restrict__ in, size_t bsIn,
                                                 u16* __restrict__ out, size_t bsOut){
  const int b = blockIdx.y;
  const float* inb = in + (size_t)b*bsIn;
  u16* outb = out + (size_t)b*bsOut;
  const size_t i4 = ((size_t)blockIdx.x*256 + threadIdx.x) * 4;
  const int k = (int)(i4 >> 9), c = (int)(i4 & 511);
  const float* row = inb + (size_t)k*HW;
  float4 a = *(const float4*)&row[c];
  float4 q = *(const float4*)&row[512 + c];
  uint2 uo;
  uo.x = (unsigned)f2bf(a.x+q.x) | ((unsigned)f2bf(a.y+q.y) << 16);
  uo.y = (unsigned)f2bf(a.z+q.z) | ((unsigned)f2bf(a.w+q.w) << 16);
  *(uint2*)&outb[i4] = uo;
}

// out-conv: + bias[m] + residual[m][n] (fp32), fp32 out pitch HW; z = batch
__global__ __launch_bounds__(256) void g_gemm_outconv(const u16* __restrict__ A, int pA,
                                                      const u16* __restrict__ B, int pB,
                                                      int K, const float* __restrict__ bias,
                                                      const float* __restrict__ res,
                                                      float* __restrict__ O,
                                                      size_t bsB, size_t bsRes, size_t bsO){
  __shared__ u16 lds[24576];
  const int b = blockIdx.z;
  TileCtx t = tctx(blockIdx.x, blockIdx.y);
  f32x4 acc[4][4]; ACC_ZERO(acc);
  mfma_core<false>(A + (size_t)blockIdx.y*128*pA, nullptr, pA,
                   B + (size_t)b*bsB + (size_t)blockIdx.x*128*pB, nullptr, pB, K, lds, acc);
  const float* resb = res + (size_t)b*bsRes;
  float* Ob = O + (size_t)b*bsO;
  #pragma unroll
  for (int fm = 0; fm < 4; ++fm)
    #pragma unroll
    for (int fn = 0; fn < 4; ++fn)
      #pragma unroll
      for (int r = 0; r < 4; ++r){
        int gm = t.wm + fm*16 + t.rq + r;
        int gn = t.wn + fn*16 + t.cn;
        Ob[(size_t)gm*HW + gn] = acc[fm][fn][r] + bias[gm] + resb[(size_t)gm*HW + gn];
      }
}

// hmid: lrelu(acc*inc[m] + b1[n]) -> fp32 out pitch HID; z = batch
__global__ __launch_bounds__(256) void g_gemm_hmid(const u16* __restrict__ A, int pA,
                                                   const u16* __restrict__ B, int pB,
                                                   int K, const float* __restrict__ inc,
                                                   const float* __restrict__ b1,
                                                   float* __restrict__ O,
                                                   size_t bsA, size_t bsP, size_t bsInc, size_t bsO){
  __shared__ u16 lds[24576];
  const int b = blockIdx.z;
  TileCtx t = tctx(blockIdx.x, blockIdx.y);
  f32x4 acc[4][4]; ACC_ZERO(acc);
  mfma_core<false>(A + (size_t)b*bsA + (size_t)blockIdx.y*128*pA, nullptr, pA,
                   B + (size_t)b*bsP + (size_t)blockIdx.x*128*pB, nullptr, pB, K, lds, acc);
  const float* incb = inc + (size_t)b*bsInc;
  float* Ob = O + (size_t)b*bsO;
  #pragma unroll
  for (int fm = 0; fm < 4; ++fm)
    #pragma unroll
    for (int fn = 0; fn < 4; ++fn)
      #pragma unroll
      for (int r = 0; r < 4; ++r){
        int gm = t.wm + fm*16 + t.rq + r;
        int gn = t.wn + fn*16 + t.cn;
        float h = acc[fm][fn][r] * incb[gm] + b1[gn];
        Ob[(size_t)gm*HID + gn] = (h > 0.f) ? h : 0.2f*h;
      }
}

// ---------------- prep kernels ----------------------------------------------
__global__ __launch_bounds__(256) void k_stats(const float* __restrict__ content,
                                               const float* __restrict__ style,
                                               float2* __restrict__ statsC,
                                               float2* __restrict__ statsS){
  const int bc = blockIdx.x;
  const float* X = (blockIdx.y == 0 ? content : style) + (size_t)bc * HW;
  float s = 0.f, sq = 0.f;
  for (int i = threadIdx.x; i < HW; i += 256){ float v = X[i]; s += v; sq += v*v; }
  s = wsum(s); sq = wsum(sq);
  __shared__ float as[4], aq[4];
  if ((threadIdx.x & 63) == 0){ as[threadIdx.x>>6] = s; aq[threadIdx.x>>6] = sq; }
  __syncthreads();
  if (threadIdx.x == 0){
    float S = as[0]+as[1]+as[2]+as[3], Q = aq[0]+aq[1]+aq[2]+aq[3];
    float mean = S / (float)HW;
    float var  = (Q - S*mean) / (float)(HW - 1);
    (blockIdx.y == 0 ? statsC : statsS)[bc] = make_float2(mean, rsqrtf(var + 1e-5f));
  }
}

// column L2 norms: 512 blocks (64 cols x 4 c-groups of 128) -> full-GPU fill
__global__ __launch_bounds__(256) void k_pixnorm(const float* __restrict__ content,
                                                 const float* __restrict__ style,
                                                 float* __restrict__ inc,
                                                 float* __restrict__ ins){
  const int b = blockIdx.y, z = blockIdx.z;
  const int k0 = blockIdx.x * 64;
  const int kk = threadIdx.x & 63, cg = threadIdx.x >> 6;
  const float* X = (z == 0 ? content : style) + (size_t)b * C * HW + k0 + kk;
  float acc = 0.f;
  for (int c = cg*128; c < cg*128 + 128; ++c){ float v = X[(size_t)c * HW]; acc += v*v; }
  __shared__ float part[4][64];
  part[cg][kk] = acc; __syncthreads();
  if (threadIdx.x < 64){
    float t = part[0][kk] + part[1][kk] + part[2][kk] + part[3][kk];
    (z == 0 ? inc : ins)[b*HW + k0 + kk] = 1.f / fmaxf(sqrtf(t), 1e-12f);
  }
}

// transpose X[C][HW] -> XT[HW][C]: mvn split (hi,lo) + raw bf16; z=1 also emits
// stS[c][l] = bf16(style[c,l]*ins[l]) on the (coalesced) load side.
// blockIdx.z = b*2 + z (z picks content/style)
__global__ __launch_bounds__(256) void k_prep2(const float* __restrict__ Xc,
                                               const float* __restrict__ Xs,
                                               const float2* __restrict__ stC,
                                               const float2* __restrict__ stSt,
                                               const float* __restrict__ ins,
                                               u16* __restrict__ ThiC, u16* __restrict__ TloC, u16* __restrict__ TrawC,
                                               u16* __restrict__ ThiS, u16* __restrict__ TloS, u16* __restrict__ TrawS,
                                               u16* __restrict__ stSo,
                                               size_t bsX, size_t bsT, int bsSt, size_t bsIns, size_t bsSo){
  const int zb = blockIdx.z, b = zb >> 1, z = zb & 1;
  const float* X = (z ? Xs : Xc) + (size_t)b*bsX;
  const float2* stats = (z ? stSt : stC) + (size_t)b*bsSt;
  u16* Thi = (z ? ThiS : ThiC) + (size_t)b*bsT;
  u16* Tlo = (z ? TloS : TloC) + (size_t)b*bsT;
  u16* Traw = (z ? TrawS : TrawC) + (size_t)b*bsT;
  u16* sSb = stSo + (size_t)b*bsSo;
  const float* insb = ins + (size_t)b*bsIns;
  __shared__ float tile[64][65];
  __shared__ float2 st[64];
  const int k0 = blockIdx.x*64, c0 = blockIdx.y*64;
  const int t = threadIdx.x;
  if (t < 64) st[t] = stats[c0 + t];
  const int j4 = (t & 15) * 4, i0 = t >> 4;
  float4 sv;
  if (z) sv = *(const float4*)&insb[k0 + j4];
  for (int r = 0; r < 4; ++r){
    int i = i0 + r*16;
    float4 v = *(const float4*)&X[(size_t)(c0+i)*HW + k0 + j4];
    tile[i][j4+0] = v.x; tile[i][j4+1] = v.y; tile[i][j4+2] = v.z; tile[i][j4+3] = v.w;
    if (z){
      u16 q0 = f2bf(v.x*sv.x), q1 = f2bf(v.y*sv.y), q2 = f2bf(v.z*sv.z), q3 = f2bf(v.w*sv.w);
      uint2 uo; uo.x = (unsigned)q0 | ((unsigned)q1 << 16);
      uo.y = (unsigned)q2 | ((unsigned)q3 << 16);
      *(uint2*)&sSb[(size_t)(c0+i)*HW + k0 + j4] = uo;
    }
  }
  __syncthreads();
  const int kk = t >> 2, cc = (t & 3) * 16;
  u16 h[16], l[16], rw[16];
  #pragma unroll
  for (int q = 0; q < 16; ++q){
    float x = tile[cc+q][kk];
    float2 s = st[cc+q];
    rw[q] = f2bf(x);
    float v = (x - s.x) * s.y;
    h[q] = f2bf(v);
    l[q] = f2bf(v - bf2f(h[q]));
  }
  size_t o = (size_t)(k0+kk)*C + c0 + cc;   // 16-u16 (32B) aligned
  *(uint4*)&Thi[o]    = pk8(h[0],h[1],h[2],h[3],h[4],h[5],h[6],h[7]);
  *(uint4*)&Thi[o+8]  = pk8(h[8],h[9],h[10],h[11],h[12],h[13],h[14],h[15]);
  *(uint4*)&Tlo[o]    = pk8(l[0],l[1],l[2],l[3],l[4],l[5],l[6],l[7]);
  *(uint4*)&Tlo[o+8]  = pk8(l[8],l[9],l[10],l[11],l[12],l[13],l[14],l[15]);
  *(uint4*)&Traw[o]   = pk8(rw[0],rw[1],rw[2],rw[3],rw[4],rw[5],rw[6],rw[7]);
  *(uint4*)&Traw[o+8] = pk8(rw[8],rw[9],rw[10],rw[11],rw[12],rw[13],rw[14],rw[15]);
}

// weight prep: split Wf,Wg ; bf16 Wh,Wout,W1
__global__ __launch_bounds__(256) void k_wprep(const float* __restrict__ Wf, const float* __restrict__ Wg,
                                               const float* __restrict__ Wh, const float* __restrict__ Wo,
                                               const float* __restrict__ W1,
                                               u16* __restrict__ Wfh, u16* __restrict__ Wfl,
                                               u16* __restrict__ Wgh, u16* __restrict__ Wgl,
                                               u16* __restrict__ Whb, u16* __restrict__ Wob,
                                               u16* __restrict__ W1b){
  const int idx = (blockIdx.x*256 + threadIdx.x) * 4;
  const int mode = blockIdx.y;
  const int nsmall = C*C;
  if (mode == 4){
    float4 v = *(const float4*)&W1[idx];
    W1b[idx+0]=f2bf(v.x); W1b[idx+1]=f2bf(v.y); W1b[idx+2]=f2bf(v.z); W1b[idx+3]=f2bf(v.w);
    return;
  }
  if (idx >= nsmall) return;
  const float* src = (mode==0)?Wf:(mode==1)?Wg:(mode==2)?Wh:Wo;
  float4 v = *(const float4*)&src[idx];
  float vv[4] = {v.x, v.y, v.z, v.w};
  if (mode <= 1){
    u16* oh = (mode==0)?Wfh:Wgh;  u16* ol = (mode==0)?Wfl:Wgl;
    #pragma unroll
    for (int q = 0; q < 4; ++q){
      u16 hh = f2bf(vv[q]);
      oh[idx+q] = hh; ol[idx+q] = f2bf(vv[q] - bf2f(hh));
    }
  } else {
    u16* ob = (mode==2)?Whb:Wob;
    #pragma unroll
    for (int q = 0; q < 4; ++q) ob[idx+q] = f2bf(vv[q]);
  }
}

// clamp[k] = 0.4 + 0.5*sigmoid(dot(hmid[k,:],W2)+b2); blockIdx.y = batch
__global__ __launch_bounds__(256) void k_psi(const float* __restrict__ hmid,
                                             const float* __restrict__ W2,
                                             const float* __restrict__ b2,
                                             float* __restrict__ clampv,
                                             size_t bsH, size_t bsC){
  const int k = blockIdx.x, tid = threadIdx.x, b = blockIdx.y;
  float v = hmid[(size_t)b*bsH + (size_t)k*HID + tid] * W2[tid];
  v = wsum(v);
  __shared__ float a[4];
  if ((tid & 63) == 0) a[tid>>6] = v;
  __syncthreads();
  if (tid == 0){
    float t = a[0]+a[1]+a[2]+a[3];
    float psi = 1.f/(1.f + __expf(-(t + b2[0])));
    clampv[(size_t)b*bsC + k] = psi*0.5f + 0.4f;
  }
}

// row softmax of T2[k,:] then sigmoid(50*(S-clamp)) -> bf16 in-place (row head)
// blockIdx.y = batch
__global__ __launch_bounds__(256) void k_softgate(float* __restrict__ T2,
                                                  const float* __restrict__ clampv,
                                                  size_t bsT, size_t bsC){
  const int k = blockIdx.x, tid = threadIdx.x, b = blockIdx.y;
  float* row = &T2[(size_t)b*bsT + (size_t)k*HW];
  float vals[16];
  float mx = -3.4e38f;
  #pragma unroll
  for (int i = 0; i < 16; ++i){ vals[i] = row[tid + i*256]; mx = fmaxf(mx, vals[i]); }
  mx = wmax(mx);
  __shared__ float am[4], asm_[4];
  if ((tid & 63) == 0) am[tid>>6] = mx;
  __syncthreads();
  mx = fmaxf(fmaxf(am[0], am[1]), fmaxf(am[2], am[3]));
  float s = 0.f;
  #pragma unroll
  for (int i = 0; i < 16; ++i){ vals[i] = __expf(vals[i] - mx); s += vals[i]; }
  s = wsum(s);
  if ((tid & 63) == 0) asm_[tid>>6] = s;
  __syncthreads();
  s = asm_[0]+asm_[1]+asm_[2]+asm_[3];
  const float inv = 1.f / s;
  const float cv = clampv[(size_t)b*bsC + k];
  u16* Sg = (u16*)row;
  #pragma unroll
  for (int i = 0; i < 16; ++i){
    float sg = 1.f/(1.f + __expf(-50.f*(vals[i]*inv - cv)));
    Sg[tid + i*256] = f2bf(sg);
  }
}

extern "C" void kernel_launch(void* const* d_in, const int* in_sizes, int n_in,
                              void* d_out, int out_size, void* d_ws, size_t ws_size,
                              hipStream_t stream){
  const float* content = (const float*)d_in[0];
  const float* style   = (const float*)d_in[1];
  const float* Wf   = (const float*)d_in[2];  const float* bfv  = (const float*)d_in[3];
  const float* Wg   = (const float*)d_in[4];  const float* bg   = (const float*)d_in[5];
  const float* Wh   = (const float*)d_in[6];  const float* bh   = (const float*)d_in[7];
  const float* Wo   = (const float*)d_in[8];  const float* bout = (const float*)d_in[9];
  const float* W1   = (const float*)d_in[10]; const float* b1   = (const float*)d_in[11];
  const float* W2   = (const float*)d_in[12]; const float* b2   = (const float*)d_in[13];
  float* out = (float*)d_out;
  (void)in_sizes; (void)n_in; (void)out_size;

  char* ws = (char*)d_ws;
  size_t off = 0;
  auto alloc = [&](size_t bytes)->void*{
    void* p = (void*)(ws + off);
    off += (bytes + 255) & ~(size_t)255;
    return p;
  };
  // ---- common allocations (all modes) ----
  float2* statsC = (float2*)alloc((size_t)Bn*C*sizeof(float2));
  float2* statsS = (float2*)alloc((size_t)Bn*C*sizeof(float2));
  float*  inc    = (float*) alloc((size_t)Bn*HW*sizeof(float));
  float*  ins    = (float*) alloc((size_t)Bn*HW*sizeof(float));
  float*  clampv = (float*) alloc((size_t)Bn*HW*sizeof(float));
  u16* Wfh = (u16*)alloc((size_t)C*C*2), *Wfl = (u16*)alloc((size_t)C*C*2);
  u16* Wgh = (u16*)alloc((size_t)C*C*2), *Wgl = (u16*)alloc((size_t)C*C*2);
  u16* Whb = (u16*)alloc((size_t)C*C*2), *Wob = (u16*)alloc((size_t)C*C*2);
  u16* W1b = (u16*)alloc((size_t)HID*HW*2);
  const size_t commonEnd = off;

  const size_t TPB = (size_t)HW*C;          // per-batch transposed-slab elems (4 MB)
  const size_t XB  = (size_t)C*HW;          // per-batch fp32 input elems
  const size_t SLB = (size_t)Bn*TPB*2;      // batched bf16 slab bytes (16 MB)

  // setup (identical in all modes)
  k_stats  <<<dim3(Bn*C, 2),       256, 0, stream>>>(content, style, statsC, statsS);
  k_pixnorm<<<dim3(HW/64, Bn, 2),  256, 0, stream>>>(content, style, inc, ins);
  k_wprep  <<<dim3(HID*HW/1024, 5),256, 0, stream>>>(Wf, Wg, Wh, Wo, W1,
                                                     Wfh, Wfl, Wgh, Wgl, Whb, Wob, W1b);

  // batched prep phase: everything before the T2 chain, 7 dispatches.
  auto runPrep = [&](char* R, u16* bFqTh, u16* bFqTl, u16* bGkTh, u16* bGkTl,
                     u16* bHvb, u16* bPT){
    u16* bXcTh = (u16*)(R + 0*SLB);
    u16* bXcTl = (u16*)(R + 1*SLB);
    u16* bXsTh = (u16*)(R + 2*SLB);
    u16* bXsTl = (u16*)(R + 3*SLB);
    u16* bCrT  = (u16*)(R + 4*SLB);
    u16* bSrT  = (u16*)(R + 5*SLB);
    u16* bstS  = (u16*)(R + 6*SLB);
    float* bPpart = (float*)(R + 0*SLB);   // 16-slice partials: slots 0-1 (dead XcT*)
    float* bhmid  = (float*)(R + 1*SLB);   // hmid overlays slot 1 AFTER reduce
    k_prep2 <<<dim3(HW/64, C/64, 2*Bn), 256, 0, stream>>>(content, style, statsC, statsS, ins,
                                                          bXcTh, bXcTl, bCrT, bXsTh, bXsTl, bSrT,
                                                          bstS, XB, TPB, C, HW, TPB);
    g_conv_split2<<<dim3(C/128, HW/128, 2*Bn), 256, 0, stream>>>(
        bXcTh, bXcTl, bXsTh, bXsTl, Wfh, Wfl, Wgh, Wgl, bfv, bg,
        bFqTh, bFqTl, bGkTh, bGkTl, TPB, TPB);
    g_gemm_biasm_bf16<<<dim3(HW/128, C/128, Bn), 256, 0, stream>>>(Whb, C, bSrT, C, C, bh,
                                                                   bHvb, HW, TPB, TPB);
    // PT: split-K 16 x 256 -> 512 blocks (2/CU)
    g_gemm_partial<<<dim3(C/128, HID/128, Bn*16), 256, 0, stream>>>(W1b, HW, bstS, HW, 256,
                                                                    bPpart, C, (size_t)HID*C, 16,
                                                                    0, TPB, (size_t)16*HID*C);
    k_reduce<<<dim3(HID*C/1024, Bn), 256, 0, stream>>>(bPpart, (size_t)HID*C, 16, bPT,
                                                       (size_t)16*HID*C, (size_t)HID*C);
    g_gemm_hmid<<<dim3(HID/128, HW/128, Bn), 256, 0, stream>>>(bCrT, C, bPT, C, C, inc, b1, bhmid,
                                                               TPB, (size_t)HID*C, HW, (size_t)HW*HID);
    k_psi<<<dim3(HW, Bn), 256, 0, stream>>>(bhmid, W2, b2, clampv, (size_t)HW*HID, HW);
  };

  // ---------------- tier 1: fully batched (~378 MB) --------------------------
  {
    size_t o = commonEnd;
    auto al = [&](size_t bytes)->void*{ void* p = (void*)(ws + o); o += (bytes + 255) & ~(size_t)255; return p; };
    u16* bFqTh = (u16*)al(SLB), *bFqTl = (u16*)al(SLB);
    u16* bGkTh = (u16*)al(SLB), *bGkTl = (u16*)al(SLB);
    u16* bHvb  = (u16*)al(SLB);
    u16* bPT   = (u16*)al((size_t)Bn*HID*C*2);
    u16* bO1T  = (u16*)al(SLB);
    char* R    = (char*)al((size_t)Bn*HW*HW*4);   // 256 MB: prep slabs, then bT2
    if (o <= ws_size){
      runPrep(R, bFqTh, bFqTl, bGkTh, bGkTl, bHvb, bPT);
      float* bT2 = (float*)R;                     // overlays all dead prep slabs
      g_gemm_split_f32<<<dim3(HW/128, HW/128, Bn), 256, 0, stream>>>(bFqTh, bFqTl, C, bGkTh, bGkTl, C,
                                                                     C, bT2, HW,
                                                                     TPB, TPB, (size_t)HW*HW);
      k_softgate<<<dim3(HW, Bn), 256, 0, stream>>>(bT2, clampv, (size_t)HW*HW, HW);
      // ogemm split-K=2, partials in T2 dead row-halves -> grid 1024 (4/CU)
      g_gemm_partial<<<dim3(C/128, HW/128, Bn*2), 256, 0, stream>>>(
          (const u16*)bT2, 2*HW, bHvb, HW, 2048,
          (float*)bT2 + 2048, HW, 512, 2,
          (size_t)HW*HW*2, TPB, (size_t)HW*HW);
      k_reduce2<<<dim3(HW*C/1024, Bn), 256, 0, stream>>>((float*)bT2 + 2048, (size_t)HW*HW,
                                                         bO1T, TPB);
      g_gemm_outconv<<<dim3(HW/128, C/128, Bn), 256, 0, stream>>>(Wob, C, bO1T, C, C, bout, content, out,
                                                                  TPB, XB, XB);
      return;
    }
  }

  // ------- tier 1.25: 2-batch T2 chunks; split-K ogemm into T2 dead halves ---
  // After softgate, only the bf16 row-heads (first 8 KB of each 16 KB T2 row)
  // are live. The dead second halves form an affine region (base +2048 floats,
  // pitch HW floats): slice sl of row k at [k*HW + 2048 + sl*512 .. +512).
  // g_gemm_partial writes there (grid 512 = 2 blk/CU vs full-K's 256 = 1/CU);
  // k_reduce2 sums the two slots. Zero extra workspace (~226 MB total).
  {
    size_t o = commonEnd;
    auto al = [&](size_t bytes)->void*{ void* p = (void*)(ws + o); o += (bytes + 255) & ~(size_t)255; return p; };
    u16* bFqTh = (u16*)al(SLB), *bFqTl = (u16*)al(SLB);
    u16* bGkTh = (u16*)al(SLB), *bGkTl = (u16*)al(SLB);
    u16* bHvb  = (u16*)al(SLB);
    u16* bPT   = (u16*)al((size_t)Bn*HID*C*2);
    char* R    = (char*)al((size_t)2*HW*HW*4 + (size_t)2*TPB*2 + 256); // 136 MB
    if (o <= ws_size){
      runPrep(R, bFqTh, bFqTl, bGkTh, bGkTl, bHvb, bPT);
      float* T2s  = (float*)R;                              // 2 x 64 MB
      u16*   O1Ts = (u16*)(R + (size_t)2*HW*HW*4);          // 2 x 4 MB
      for (int cb = 0; cb < Bn; cb += 2){
        g_gemm_split_f32<<<dim3(HW/128, HW/128, 2), 256, 0, stream>>>(
            bFqTh + (size_t)cb*TPB, bFqTl + (size_t)cb*TPB, C,
            bGkTh + (size_t)cb*TPB, bGkTl + (size_t)cb*TPB, C, C, T2s, HW,
            TPB, TPB, (size_t)HW*HW);
        k_softgate<<<dim3(HW, 2), 256, 0, stream>>>(T2s, clampv + (size_t)cb*HW,
                                                    (size_t)HW*HW, HW);
        g_gemm_partial<<<dim3(C/128, HW/128, 4), 256, 0, stream>>>(
            (const u16*)T2s, 2*HW, bHvb + (size_t)cb*TPB, HW, 2048,
            T2s + 2048, HW, 512, 2,
            (size_t)HW*HW*2, TPB, (size_t)HW*HW);
        k_reduce2<<<dim3(HW*C/1024, 2), 256, 0, stream>>>(T2s + 2048, (size_t)HW*HW,
                                                          O1Ts, TPB);
        g_gemm_outconv<<<dim3(HW/128, C/128, 2), 256, 0, stream>>>(
            Wob, C, O1Ts, C, C, bout, content + (size_t)cb*XB, out + (size_t)cb*XB,
            TPB, XB, XB);
      }
      return;
    }
  }

  // ---------------- tier 1.5: batched prep + per-batch T2 chain (~199 MB) ----
  {
    size_t o = commonEnd;
    auto al = [&](size_t bytes)->void*{ void* p = (void*)(ws + o); o += (bytes + 255) & ~(size_t)255; return p; };
    u16* bFqTh = (u16*)al(SLB), *bFqTl = (u16*)al(SLB);
    u16* bGkTh = (u16*)al(SLB), *bGkTl = (u16*)al(SLB);
    u16* bHvb  = (u16*)al(SLB);
    u16* bPT   = (u16*)al((size_t)Bn*HID*C*2);
    char* R    = (char*)al(7*SLB);                // 112 MB: prep slabs, then chain scratch
    if (o <= ws_size){
      runPrep(R, bFqTh, bFqTl, bGkTh, bGkTl, bHvb, bPT);
      float* T2s   = (float*)(R + 0*SLB);         // 64 MB (slots 0-3, dead)
      u16*   O1Ts  = (u16*)  (R + 6*SLB);         //  4 MB (slot 6, dead)
      for (int b = 0; b < Bn; ++b){
        g_gemm_split_f32<<<dim3(HW/128, HW/128), 256, 0, stream>>>(
            bFqTh + (size_t)b*TPB, bFqTl + (size_t)b*TPB, C,
            bGkTh + (size_t)b*TPB, bGkTl + (size_t)b*TPB, C, C, T2s, HW, 0, 0, 0);
        k_softgate<<<dim3(HW), 256, 0, stream>>>(T2s, clampv + (size_t)b*HW, 0, 0);
        g_gemm_partial<<<dim3(C/128, HW/128, 2), 256, 0, stream>>>(
            (const u16*)T2s, 2*HW, bHvb + (size_t)b*TPB, HW, 2048,
            T2s + 2048, HW, 512, 2,
            0, 0, 0);
        k_reduce2<<<dim3(HW*C/1024), 256, 0, stream>>>(T2s + 2048, 0, O1Ts, 0);
        g_gemm_outconv<<<dim3(HW/128, C/128), 256, 0, stream>>>(Wob, C, O1Ts, C, C, bout,
            content + (size_t)b*XB, out + (size_t)b*XB, 0, 0, 0);
      }
      return;
    }
  }

  // ---------------- fallback: proven per-batch path (~170 MB) ----------------
  off = commonEnd;
  u16* XcTh = (u16*)alloc((size_t)HW*C*2), *XcTl = (u16*)alloc((size_t)HW*C*2);
  u16* CrT  = (u16*)alloc((size_t)HW*C*2);
  u16* XsTh = (u16*)alloc((size_t)HW*C*2), *XsTl = (u16*)alloc((size_t)HW*C*2);
  u16* SrT  = (u16*)alloc((size_t)HW*C*2);
  u16* stS  = (u16*)alloc((size_t)C*HW*2);
  u16* FqTh = (u16*)alloc((size_t)HW*C*2), *FqTl = (u16*)alloc((size_t)HW*C*2);
  u16* GkTh = (u16*)alloc((size_t)HW*C*2), *GkTl = (u16*)alloc((size_t)HW*C*2);
  u16* Hvb  = (u16*)alloc((size_t)C*HW*2);
  u16* O1T  = (u16*)alloc((size_t)HW*C*2);
  u16* PT   = (u16*)alloc((size_t)HID*C*2);
  float* hmid  = (float*)alloc((size_t)HW*HID*sizeof(float));
  float* Ppart = (float*)alloc((size_t)16*HID*C*sizeof(float));   // 8 MB
  float* T2    = (float*)alloc((size_t)HW*HW*sizeof(float));      // 64 MB

  for (int b = 0; b < Bn; ++b){
    const float* cb = content + (size_t)b*C*HW;
    const float* sb = style   + (size_t)b*C*HW;
    const float* incb = inc + (size_t)b*HW;
    const float* insb = ins + (size_t)b*HW;
    float* clb = clampv + (size_t)b*HW;

    k_prep2 <<<dim3(HW/64, C/64, 2), 256, 0, stream>>>(cb, sb, statsC + (size_t)b*C, statsS + (size_t)b*C,
                                                       insb, XcTh, XcTl, CrT, XsTh, XsTl, SrT,
                                                       stS, 0, 0, 0, 0, 0);
    g_conv_split2<<<dim3(C/128, HW/128, 2), 256, 0, stream>>>(
        XcTh, XcTl, XsTh, XsTl, Wfh, Wfl, Wgh, Wgl, bfv, bg,
        FqTh, FqTl, GkTh, GkTl, 0, 0);
    g_gemm_biasm_bf16<<<dim3(HW/128, C/128), 256, 0, stream>>>(Whb, C, SrT, C, C, bh, Hvb, HW, 0, 0);
    g_gemm_partial<<<dim3(C/128, HID/128, 16), 256, 0, stream>>>(W1b, HW, stS, HW, 256,
                                                                 Ppart, C, (size_t)HID*C, 16, 0, 0, 0);
    k_reduce<<<dim3(HID*C/1024), 256, 0, stream>>>(Ppart, (size_t)HID*C, 16, PT, 0, 0);
    g_gemm_hmid<<<dim3(HID/128, HW/128), 256, 0, stream>>>(CrT, C, PT, C, C, incb, b1, hmid, 0, 0, 0, 0);
    k_psi<<<dim3(HW), 256, 0, stream>>>(hmid, W2, b2, clb, 0, 0);
    g_gemm_split_f32<<<dim3(HW/128, HW/128), 256, 0, stream>>>(FqTh, FqTl, C, GkTh, GkTl, C, C, T2, HW, 0, 0, 0);
    k_softgate<<<dim3(HW), 256, 0, stream>>>(T2, clb, 0, 0);
    g_gemm_partial<<<dim3(C/128, HW/128, 2), 256, 0, stream>>>(
        (const u16*)T2, 2*HW, Hvb, HW, 2048, T2 + 2048, HW, 512, 2, 0, 0, 0);
    k_reduce2<<<dim3(HW*C/1024), 256, 0, stream>>>(T2 + 2048, 0, O1T, 0);
    g_gemm_outconv<<<dim3(HW/128, C/128), 256, 0, stream>>>(Wob, C, O1T, C, C, bout, cb,
                                                            out + (size_t)b*C*HW, 0, 0, 0);
  }
}

// Round 9
// 740.816 us; speedup vs baseline: 1.0507x; 1.0507x over previous
//
#include <hip/hip_runtime.h>

typedef unsigned short u16;
typedef __attribute__((ext_vector_type(8))) short short8;   // 8 bf16 (4 VGPRs)
typedef __attribute__((ext_vector_type(4))) float f32x4;    // MFMA acc

static constexpr int Bn  = 4;
static constexpr int C   = 512;
static constexpr int HW  = 4096;
static constexpr int HID = 256;

__device__ __forceinline__ float bf2f(u16 u){
  union { unsigned int i; float f; } x; x.i = ((unsigned int)u) << 16; return x.f;
}
__device__ __forceinline__ u16 f2bf(float f){
  union { float f; unsigned int i; } x; x.f = f;
  return (u16)((x.i + 0x7fffu + ((x.i >> 16) & 1u)) >> 16);
}
__device__ __forceinline__ float wsum(float v){
  #pragma unroll
  for (int o = 32; o > 0; o >>= 1) v += __shfl_xor(v, o, 64);
  return v;
}
__device__ __forceinline__ float wmax(float v){
  #pragma unroll
  for (int o = 32; o > 0; o >>= 1) v = fmaxf(v, __shfl_xor(v, o, 64));
  return v;
}
__device__ __forceinline__ uint4 pk8(u16 a,u16 b,u16 c,u16 d,u16 e,u16 f,u16 g,u16 h){
  uint4 r; r.x=(unsigned)a|((unsigned)b<<16); r.y=(unsigned)c|((unsigned)d<<16);
  r.z=(unsigned)e|((unsigned)f<<16); r.w=(unsigned)g|((unsigned)h<<16); return r;
}
// NOTE (R5 post-mortem): XCD "contiguous chunk" swizzle REGRESSED (FETCH
// 86->261 MB). Default round-robin dispatch already gives each XCD an
// L2-fitting A+B panel scatter. Identity mapping kept.
// NOTE (R8 post-mortem): 3-buffer 2-deep plain core + ogemm split-K into T2
// dead halves REGRESSED (747.6 -> 778.4): per-K-step barrier re-serializes
// regardless of staging depth, and fp32 partial round-trip costs ~110 MB HBM.
// Reverted to the proven R6 structure.
// async global->LDS DMA, 16B per lane; lds dest = wave-uniform base + lane*16
__device__ __forceinline__ void gld16(const u16* g, u16* l){
  __builtin_amdgcn_global_load_lds((const __attribute__((address_space(1))) void*)g,
                                   (__attribute__((address_space(3))) void*)l, 16, 0, 0);
}

// ---------------- MFMA core: 128x128 block tile, 4 waves, DMA-staged --------
// A: M x K row-major bf16 (pitch pA), B: N x K row-major bf16 (pitch pB) -> NT
// BK=32, double-buffered LDS, counted vmcnt (never 0 in-loop).
// XOR bank-swizzle (both-sides, rule #21): read chunk = kq ^ ((fr>>1)&3);
// global source pre-permuted per lane: (l&3)^((l>>3)&3). Measured: bank
// conflicts 4.19M -> 0, MfmaUtil 28 -> 39% (R4).
// SPLIT=true: A=Ah+Al, B=Bh+Bl, 3 passes (hh, h*l, l*h) for ~fp32 accuracy.
template<bool SPLIT>
__device__ __forceinline__ void mfma_core(const u16* __restrict__ Ah, const u16* __restrict__ Al, int pA,
                                          const u16* __restrict__ Bh, const u16* __restrict__ Bl, int pB,
                                          int K, u16* lds, f32x4 (&acc)[4][4]){
  const int tid  = threadIdx.x;
  const int lane = tid & 63, wave = tid >> 6;
  const int fr = lane & 15, kq = lane >> 4;      // frag row / k-quad
  const int kqs = (kq ^ ((fr >> 1) & 3)) * 8;    // swizzled k-chunk (u16 idx)
  const int wm = (wave & 1) * 64, wn = (wave >> 1) * 64;
  constexpr int HB = SPLIT ? 16384 : 8192;       // u16 per dbuf half (32/16 KB)
  const int srow = wave*32 + (lane >> 2);        // staging row (+i*16), i in {0,1}
  const int sq   = (((lane & 3) ^ ((lane >> 3) & 3))) * 8;  // inverse-swz src k
  const size_t ga = (size_t)srow * pA + sq;
  const size_t gb = (size_t)srow * pB + sq;
  const int ldsc = wave * 1024;                  // wave chunk base (u16 idx)

  auto stage = [&](int buf, int k0){
    u16* L = lds + buf*HB;
    #pragma unroll
    for (int i = 0; i < 2; ++i){
      gld16(Ah + ga + (size_t)i*16*pA + k0, L + ldsc + i*512);
      gld16(Bh + gb + (size_t)i*16*pB + k0, L + 4096 + ldsc + i*512);
      if constexpr (SPLIT){
        gld16(Al + ga + (size_t)i*16*pA + k0, L + 8192  + ldsc + i*512);
        gld16(Bl + gb + (size_t)i*16*pB + k0, L + 12288 + ldsc + i*512);
      }
    }
  };
  auto compute = [&](int buf){
    u16* L = lds + buf*HB;
    short8 a[4], b[4];
    #pragma unroll
    for (int i = 0; i < 4; ++i){
      a[i] = *(const short8*)&L[(wm + i*16 + fr)*32 + kqs];
      b[i] = *(const short8*)&L[4096 + (wn + i*16 + fr)*32 + kqs];
    }
    #pragma unroll
    for (int i = 0; i < 4; ++i)
      #pragma unroll
      for (int j = 0; j < 4; ++j)
        acc[i][j] = __builtin_amdgcn_mfma_f32_16x16x32_bf16(a[i], b[j], acc[i][j], 0, 0, 0);
    if constexpr (SPLIT){
      short8 a2[4], b2[4];
      #pragma unroll
      for (int i = 0; i < 4; ++i){
        a2[i] = *(const short8*)&L[8192  + (wm + i*16 + fr)*32 + kqs];
        b2[i] = *(const short8*)&L[12288 + (wn + i*16 + fr)*32 + kqs];
      }
      #pragma unroll
      for (int i = 0; i < 4; ++i)
        #pragma unroll
        for (int j = 0; j < 4; ++j){
          acc[i][j] = __builtin_amdgcn_mfma_f32_16x16x32_bf16(a[i],  b2[j], acc[i][j], 0, 0, 0);
          acc[i][j] = __builtin_amdgcn_mfma_f32_16x16x32_bf16(a2[i], b[j],  acc[i][j], 0, 0, 0);
        }
    }
  };

  stage(0, 0);
  int cur = 0;
  for (int k0 = 32; k0 < K; k0 += 32){
    stage(cur ^ 1, k0);                       // prefetch next K-step (in flight)
    if constexpr (SPLIT) asm volatile("s_waitcnt vmcnt(8)" ::: "memory");
    else                 asm volatile("s_waitcnt vmcnt(4)" ::: "memory");
    __builtin_amdgcn_s_barrier();             // all waves' cur-buffer DMA landed
    compute(cur);
    __builtin_amdgcn_s_barrier();             // reads done before next overwrite
    cur ^= 1;
  }
  asm volatile("s_waitcnt vmcnt(0)" ::: "memory");
  __builtin_amdgcn_s_barrier();
  compute(cur);
}

struct TileCtx { int wm, wn, cn, rq; };
__device__ __forceinline__ TileCtx tctx(int bx, int by){
  TileCtx t;
  const int wave = threadIdx.x >> 6, lane = threadIdx.x & 63;
  t.wm = by * 128 + (wave & 1) * 64;
  t.wn = bx * 128 + (wave >> 1) * 64;
  t.cn = lane & 15; t.rq = (lane >> 4) * 4;
  return t;
}
#define ACC_ZERO(acc) { _Pragma("unroll") for (int i=0;i<4;++i) _Pragma("unroll") for (int j=0;j<4;++j) _Pragma("unroll") for (int r=0;r<4;++r) acc[i][j][r]=0.f; }

// merged Fq/Gk conv: blockIdx.z = b*2 + z (z=0: content->Fq, z=1: style->Gk)
__global__ __launch_bounds__(256) void g_conv_split2(const u16* __restrict__ A0h, const u16* __restrict__ A0l,
                                                     const u16* __restrict__ A1h, const u16* __restrict__ A1l,
                                                     const u16* __restrict__ B0h, const u16* __restrict__ B0l,
                                                     const u16* __restrict__ B1h, const u16* __restrict__ B1l,
                                                     const float* __restrict__ bias0, const float* __restrict__ bias1,
                                                     u16* __restrict__ O0h, u16* __restrict__ O0l,
                                                     u16* __restrict__ O1h, u16* __restrict__ O1l,
                                                     size_t bsA, size_t bsO){
  __shared__ u16 lds[32768];   // 64 KB: 2 x (Ah,Bh,Al,Bl)
  const int zb = blockIdx.z, b = zb >> 1, z = zb & 1;
  const u16* Ah = (z ? A1h : A0h) + (size_t)b*bsA;  const u16* Al = (z ? A1l : A0l) + (size_t)b*bsA;
  const u16* Bh = z ? B1h : B0h;  const u16* Bl = z ? B1l : B0l;   // weights, shared
  const float* bias = z ? bias1 : bias0;
  u16* Ohi = (z ? O1h : O0h) + (size_t)b*bsO;  u16* Olo = (z ? O1l : O0l) + (size_t)b*bsO;
  TileCtx t = tctx(blockIdx.x, blockIdx.y);
  f32x4 acc[4][4]; ACC_ZERO(acc);
  mfma_core<true>(Ah + (size_t)blockIdx.y*128*C, Al + (size_t)blockIdx.y*128*C, C,
                  Bh + (size_t)blockIdx.x*128*C, Bl + (size_t)blockIdx.x*128*C, C, C, lds, acc);
  #pragma unroll
  for (int fm = 0; fm < 4; ++fm)
    #pragma unroll
    for (int fn = 0; fn < 4; ++fn)
      #pragma unroll
      for (int r = 0; r < 4; ++r){
        int gm = t.wm + fm*16 + t.rq + r;
        int gn = t.wn + fn*16 + t.cn;
        float v = acc[fm][fn][r] + bias[gn];
        u16 h = f2bf(v);
        Ohi[(size_t)gm*C + gn] = h;
        Olo[(size_t)gm*C + gn] = f2bf(v - bf2f(h));
      }
}

// split GEMM -> fp32 out (score logits T2); blockIdx.z = batch
__global__ __launch_bounds__(256) void g_gemm_split_f32(const u16* __restrict__ Ah, const u16* __restrict__ Al, int pA,
                                                        const u16* __restrict__ Bh, const u16* __restrict__ Bl, int pB,
                                                        int K, float* __restrict__ O, int pO,
                                                        size_t bsA, size_t bsB, size_t bsO){
  __shared__ u16 lds[32768];
  const int b = blockIdx.z;
  TileCtx t = tctx(blockIdx.x, blockIdx.y);
  f32x4 acc[4][4]; ACC_ZERO(acc);
  mfma_core<true>(Ah + (size_t)b*bsA + (size_t)blockIdx.y*128*pA,
                  Al + (size_t)b*bsA + (size_t)blockIdx.y*128*pA, pA,
                  Bh + (size_t)b*bsB + (size_t)blockIdx.x*128*pB,
                  Bl + (size_t)b*bsB + (size_t)blockIdx.x*128*pB, pB, K, lds, acc);
  float* Ob = O + (size_t)b*bsO;
  #pragma unroll
  for (int fm = 0; fm < 4; ++fm)
    #pragma unroll
    for (int fn = 0; fn < 4; ++fn)
      #pragma unroll
      for (int r = 0; r < 4; ++r)
        Ob[(size_t)(t.wm + fm*16 + t.rq + r)*pO + t.wn + fn*16 + t.cn] = acc[fm][fn][r];
}

// plain GEMM + bias[m] -> bf16 out (Hv conv); A (weights) shared, z = batch
__global__ __launch_bounds__(256) void g_gemm_biasm_bf16(const u16* __restrict__ A, int pA,
                                                         const u16* __restrict__ B, int pB,
                                                         int K, const float* __restrict__ bias,
                                                         u16* __restrict__ O, int pO,
                                                         size_t bsB, size_t bsO){
  __shared__ u16 lds[16384];   // 32 KB: 2 x (A,B)
  const int b = blockIdx.z;
  TileCtx t = tctx(blockIdx.x, blockIdx.y);
  f32x4 acc[4][4]; ACC_ZERO(acc);
  mfma_core<false>(A + (size_t)blockIdx.y*128*pA, nullptr, pA,
                   B + (size_t)b*bsB + (size_t)blockIdx.x*128*pB, nullptr, pB, K, lds, acc);
  u16* Ob = O + (size_t)b*bsO;
  #pragma unroll
  for (int fm = 0; fm < 4; ++fm)
    #pragma unroll
    for (int fn = 0; fn < 4; ++fn)
      #pragma unroll
      for (int r = 0; r < 4; ++r){
        int gm = t.wm + fm*16 + t.rq + r;
        Ob[(size_t)gm*pO + t.wn + fn*16 + t.cn] = f2bf(acc[fm][fn][r] + bias[gm]);
      }
}

// plain GEMM -> bf16 out, no bias; z = batch
__global__ __launch_bounds__(256) void g_gemm_plain_bf16(const u16* __restrict__ A, int pA,
                                                         const u16* __restrict__ B, int pB,
                                                         int K, u16* __restrict__ O, int pO,
                                                         size_t bsA, size_t bsB, size_t bsO){
  __shared__ u16 lds[16384];
  const int b = blockIdx.z;
  TileCtx t = tctx(blockIdx.x, blockIdx.y);
  f32x4 acc[4][4]; ACC_ZERO(acc);
  mfma_core<false>(A + (size_t)b*bsA + (size_t)blockIdx.y*128*pA, nullptr, pA,
                   B + (size_t)b*bsB + (size_t)blockIdx.x*128*pB, nullptr, pB, K, lds, acc);
  u16* Ob = O + (size_t)b*bsO;
  #pragma unroll
  for (int fm = 0; fm < 4; ++fm)
    #pragma unroll
    for (int fn = 0; fn < 4; ++fn)
      #pragma unroll
      for (int r = 0; r < 4; ++r){
        int gm = t.wm + fm*16 + t.rq + r;
        Ob[(size_t)gm*pO + t.wn + fn*16 + t.cn] = f2bf(acc[fm][fn][r]);
      }
}

// split-K GEMM -> fp32 partials; blockIdx.z = b*slices + slice
__global__ __launch_bounds__(256) void g_gemm_partial(const u16* __restrict__ A, int pA,
                                                      const u16* __restrict__ B, int pB,
                                                      int Kper, float* __restrict__ O, int pO,
                                                      size_t sliceStride, int slices,
                                                      size_t bsA, size_t bsB, size_t bsO){
  __shared__ u16 lds[16384];
  const int zz = blockIdx.z;
  const int b = zz / slices, sl = zz - b*slices;
  TileCtx t = tctx(blockIdx.x, blockIdx.y);
  const int koff = sl * Kper;
  f32x4 acc[4][4]; ACC_ZERO(acc);
  mfma_core<false>(A + (size_t)b*bsA + (size_t)blockIdx.y*128*pA + koff, nullptr, pA,
                   B + (size_t)b*bsB + (size_t)blockIdx.x*128*pB + koff, nullptr, pB, Kper, lds, acc);
  float* Oz = O + (size_t)b*bsO + (size_t)sl * sliceStride;
  #pragma unroll
  for (int fm = 0; fm < 4; ++fm)
    #pragma unroll
    for (int fn = 0; fn < 4; ++fn)
      #pragma unroll
      for (int r = 0; r < 4; ++r)
        Oz[(size_t)(t.wm + fm*16 + t.rq + r)*pO + t.wn + fn*16 + t.cn] = acc[fm][fn][r];
}

// reduce S fp32 partials -> bf16 (4 elems/thread); blockIdx.y = batch
__global__ __launch_bounds__(256) void k_reduce(const float* __restrict__ in, size_t sliceStride,
                                                int S, u16* __restrict__ out,
                                                size_t bsIn, size_t bsOut){
  const int b = blockIdx.y;
  const float* inb = in + (size_t)b*bsIn;
  u16* outb = out + (size_t)b*bsOut;
  const size_t i4 = ((size_t)blockIdx.x*256 + threadIdx.x) * 4;
  float4 s = *(const float4*)&inb[i4];
  for (int z = 1; z < S; ++z){
    float4 v = *(const float4*)&inb[(size_t)z*sliceStride + i4];
    s.x += v.x; s.y += v.y; s.z += v.z; s.w += v.w;
  }
  u16 r0 = f2bf(s.x), r1 = f2bf(s.y), r2 = f2bf(s.z), r3 = f2bf(s.w);
  uint2 uo; uo.x = (unsigned)r0 | ((unsigned)r1 << 16);
  uo.y = (unsigned)r2 | ((unsigned)r3 << 16);
  *(uint2*)&outb[i4] = uo;
}

// out-conv: + bias[m] + residual[m][n] (fp32), fp32 out pitch HW; z = batch
__global__ __launch_bounds__(256) void g_gemm_outconv(const u16* __restrict__ A, int pA,
                                                      const u16* __restrict__ B, int pB,
                                                      int K, const float* __restrict__ bias,
                                                      const float* __restrict__ res,
                                                      float* __restrict__ O,
                                                      size_t bsB, size_t bsRes, size_t bsO){
  __shared__ u16 lds[16384];
  const int b = blockIdx.z;
  TileCtx t = tctx(blockIdx.x, blockIdx.y);
  f32x4 acc[4][4]; ACC_ZERO(acc);
  mfma_core<false>(A + (size_t)blockIdx.y*128*pA, nullptr, pA,
                   B + (size_t)b*bsB + (size_t)blockIdx.x*128*pB, nullptr, pB, K, lds, acc);
  const float* resb = res + (size_t)b*bsRes;
  float* Ob = O + (size_t)b*bsO;
  #pragma unroll
  for (int fm = 0; fm < 4; ++fm)
    #pragma unroll
    for (int fn = 0; fn < 4; ++fn)
      #pragma unroll
      for (int r = 0; r < 4; ++r){
        int gm = t.wm + fm*16 + t.rq + r;
        int gn = t.wn + fn*16 + t.cn;
        Ob[(size_t)gm*HW + gn] = acc[fm][fn][r] + bias[gm] + resb[(size_t)gm*HW + gn];
      }
}

// hmid: lrelu(acc*inc[m] + b1[n]) -> fp32 out pitch HID; z = batch
__global__ __launch_bounds__(256) void g_gemm_hmid(const u16* __restrict__ A, int pA,
                                                   const u16* __restrict__ B, int pB,
                                                   int K, const float* __restrict__ inc,
                                                   const float* __restrict__ b1,
                                                   float* __restrict__ O,
                                                   size_t bsA, size_t bsP, size_t bsInc, size_t bsO){
  __shared__ u16 lds[16384];
  const int b = blockIdx.z;
  TileCtx t = tctx(blockIdx.x, blockIdx.y);
  f32x4 acc[4][4]; ACC_ZERO(acc);
  mfma_core<false>(A + (size_t)b*bsA + (size_t)blockIdx.y*128*pA, nullptr, pA,
                   B + (size_t)b*bsP + (size_t)blockIdx.x*128*pB, nullptr, pB, K, lds, acc);
  const float* incb = inc + (size_t)b*bsInc;
  float* Ob = O + (size_t)b*bsO;
  #pragma unroll
  for (int fm = 0; fm < 4; ++fm)
    #pragma unroll
    for (int fn = 0; fn < 4; ++fn)
      #pragma unroll
      for (int r = 0; r < 4; ++r){
        int gm = t.wm + fm*16 + t.rq + r;
        int gn = t.wn + fn*16 + t.cn;
        float h = acc[fm][fn][r] * incb[gm] + b1[gn];
        Ob[(size_t)gm*HID + gn] = (h > 0.f) ? h : 0.2f*h;
      }
}

// ---------------- prep kernels ----------------------------------------------
__global__ __launch_bounds__(256) void k_stats(const float* __restrict__ content,
                                               const float* __restrict__ style,
                                               float2* __restrict__ statsC,
                                               float2* __restrict__ statsS){
  const int bc = blockIdx.x;
  const float* X = (blockIdx.y == 0 ? content : style) + (size_t)bc * HW;
  float s = 0.f, sq = 0.f;
  for (int i = threadIdx.x; i < HW; i += 256){ float v = X[i]; s += v; sq += v*v; }
  s = wsum(s); sq = wsum(sq);
  __shared__ float as[4], aq[4];
  if ((threadIdx.x & 63) == 0){ as[threadIdx.x>>6] = s; aq[threadIdx.x>>6] = sq; }
  __syncthreads();
  if (threadIdx.x == 0){
    float S = as[0]+as[1]+as[2]+as[3], Q = aq[0]+aq[1]+aq[2]+aq[3];
    float mean = S / (float)HW;
    float var  = (Q - S*mean) / (float)(HW - 1);
    (blockIdx.y == 0 ? statsC : statsS)[bc] = make_float2(mean, rsqrtf(var + 1e-5f));
  }
}

// column L2 norms: 512 blocks (64 cols x 4 c-groups of 128) -> full-GPU fill
__global__ __launch_bounds__(256) void k_pixnorm(const float* __restrict__ content,
                                                 const float* __restrict__ style,
                                                 float* __restrict__ inc,
                                                 float* __restrict__ ins){
  const int b = blockIdx.y, z = blockIdx.z;
  const int k0 = blockIdx.x * 64;
  const int kk = threadIdx.x & 63, cg = threadIdx.x >> 6;
  const float* X = (z == 0 ? content : style) + (size_t)b * C * HW + k0 + kk;
  float acc = 0.f;
  for (int c = cg*128; c < cg*128 + 128; ++c){ float v = X[(size_t)c * HW]; acc += v*v; }
  __shared__ float part[4][64];
  part[cg][kk] = acc; __syncthreads();
  if (threadIdx.x < 64){
    float t = part[0][kk] + part[1][kk] + part[2][kk] + part[3][kk];
    (z == 0 ? inc : ins)[b*HW + k0 + kk] = 1.f / fmaxf(sqrtf(t), 1e-12f);
  }
}

// transpose X[C][HW] -> XT[HW][C]: mvn split (hi,lo) + raw bf16; z=1 also emits
// stS[c][l] = bf16(style[c,l]*ins[l]) on the (coalesced) load side.
// blockIdx.z = b*2 + z (z picks content/style)
__global__ __launch_bounds__(256) void k_prep2(const float* __restrict__ Xc,
                                               const float* __restrict__ Xs,
                                               const float2* __restrict__ stC,
                                               const float2* __restrict__ stSt,
                                               const float* __restrict__ ins,
                                               u16* __restrict__ ThiC, u16* __restrict__ TloC, u16* __restrict__ TrawC,
                                               u16* __restrict__ ThiS, u16* __restrict__ TloS, u16* __restrict__ TrawS,
                                               u16* __restrict__ stSo,
                                               size_t bsX, size_t bsT, int bsSt, size_t bsIns, size_t bsSo){
  const int zb = blockIdx.z, b = zb >> 1, z = zb & 1;
  const float* X = (z ? Xs : Xc) + (size_t)b*bsX;
  const float2* stats = (z ? stSt : stC) + (size_t)b*bsSt;
  u16* Thi = (z ? ThiS : ThiC) + (size_t)b*bsT;
  u16* Tlo = (z ? TloS : TloC) + (size_t)b*bsT;
  u16* Traw = (z ? TrawS : TrawC) + (size_t)b*bsT;
  u16* sSb = stSo + (size_t)b*bsSo;
  const float* insb = ins + (size_t)b*bsIns;
  __shared__ float tile[64][65];
  __shared__ float2 st[64];
  const int k0 = blockIdx.x*64, c0 = blockIdx.y*64;
  const int t = threadIdx.x;
  if (t < 64) st[t] = stats[c0 + t];
  const int j4 = (t & 15) * 4, i0 = t >> 4;
  float4 sv;
  if (z) sv = *(const float4*)&insb[k0 + j4];
  for (int r = 0; r < 4; ++r){
    int i = i0 + r*16;
    float4 v = *(const float4*)&X[(size_t)(c0+i)*HW + k0 + j4];
    tile[i][j4+0] = v.x; tile[i][j4+1] = v.y; tile[i][j4+2] = v.z; tile[i][j4+3] = v.w;
    if (z){
      u16 q0 = f2bf(v.x*sv.x), q1 = f2bf(v.y*sv.y), q2 = f2bf(v.z*sv.z), q3 = f2bf(v.w*sv.w);
      uint2 uo; uo.x = (unsigned)q0 | ((unsigned)q1 << 16);
      uo.y = (unsigned)q2 | ((unsigned)q3 << 16);
      *(uint2*)&sSb[(size_t)(c0+i)*HW + k0 + j4] = uo;
    }
  }
  __syncthreads();
  const int kk = t >> 2, cc = (t & 3) * 16;
  u16 h[16], l[16], rw[16];
  #pragma unroll
  for (int q = 0; q < 16; ++q){
    float x = tile[cc+q][kk];
    float2 s = st[cc+q];
    rw[q] = f2bf(x);
    float v = (x - s.x) * s.y;
    h[q] = f2bf(v);
    l[q] = f2bf(v - bf2f(h[q]));
  }
  size_t o = (size_t)(k0+kk)*C + c0 + cc;   // 16-u16 (32B) aligned
  *(uint4*)&Thi[o]    = pk8(h[0],h[1],h[2],h[3],h[4],h[5],h[6],h[7]);
  *(uint4*)&Thi[o+8]  = pk8(h[8],h[9],h[10],h[11],h[12],h[13],h[14],h[15]);
  *(uint4*)&Tlo[o]    = pk8(l[0],l[1],l[2],l[3],l[4],l[5],l[6],l[7]);
  *(uint4*)&Tlo[o+8]  = pk8(l[8],l[9],l[10],l[11],l[12],l[13],l[14],l[15]);
  *(uint4*)&Traw[o]   = pk8(rw[0],rw[1],rw[2],rw[3],rw[4],rw[5],rw[6],rw[7]);
  *(uint4*)&Traw[o+8] = pk8(rw[8],rw[9],rw[10],rw[11],rw[12],rw[13],rw[14],rw[15]);
}

// weight prep: split Wf,Wg ; bf16 Wh,Wout,W1
__global__ __launch_bounds__(256) void k_wprep(const float* __restrict__ Wf, const float* __restrict__ Wg,
                                               const float* __restrict__ Wh, const float* __restrict__ Wo,
                                               const float* __restrict__ W1,
                                               u16* __restrict__ Wfh, u16* __restrict__ Wfl,
                                               u16* __restrict__ Wgh, u16* __restrict__ Wgl,
                                               u16* __restrict__ Whb, u16* __restrict__ Wob,
                                               u16* __restrict__ W1b){
  const int idx = (blockIdx.x*256 + threadIdx.x) * 4;
  const int mode = blockIdx.y;
  const int nsmall = C*C;
  if (mode == 4){
    float4 v = *(const float4*)&W1[idx];
    W1b[idx+0]=f2bf(v.x); W1b[idx+1]=f2bf(v.y); W1b[idx+2]=f2bf(v.z); W1b[idx+3]=f2bf(v.w);
    return;
  }
  if (idx >= nsmall) return;
  const float* src = (mode==0)?Wf:(mode==1)?Wg:(mode==2)?Wh:Wo;
  float4 v = *(const float4*)&src[idx];
  float vv[4] = {v.x, v.y, v.z, v.w};
  if (mode <= 1){
    u16* oh = (mode==0)?Wfh:Wgh;  u16* ol = (mode==0)?Wfl:Wgl;
    #pragma unroll
    for (int q = 0; q < 4; ++q){
      u16 hh = f2bf(vv[q]);
      oh[idx+q] = hh; ol[idx+q] = f2bf(vv[q] - bf2f(hh));
    }
  } else {
    u16* ob = (mode==2)?Whb:Wob;
    #pragma unroll
    for (int q = 0; q < 4; ++q) ob[idx+q] = f2bf(vv[q]);
  }
}

// clamp[k] = 0.4 + 0.5*sigmoid(dot(hmid[k,:],W2)+b2); blockIdx.y = batch
__global__ __launch_bounds__(256) void k_psi(const float* __restrict__ hmid,
                                             const float* __restrict__ W2,
                                             const float* __restrict__ b2,
                                             float* __restrict__ clampv,
                                             size_t bsH, size_t bsC){
  const int k = blockIdx.x, tid = threadIdx.x, b = blockIdx.y;
  float v = hmid[(size_t)b*bsH + (size_t)k*HID + tid] * W2[tid];
  v = wsum(v);
  __shared__ float a[4];
  if ((tid & 63) == 0) a[tid>>6] = v;
  __syncthreads();
  if (tid == 0){
    float t = a[0]+a[1]+a[2]+a[3];
    float psi = 1.f/(1.f + __expf(-(t + b2[0])));
    clampv[(size_t)b*bsC + k] = psi*0.5f + 0.4f;
  }
}

// row softmax of T2[k,:] then sigmoid(50*(S-clamp)) -> bf16 in-place (row head)
// blockIdx.y = batch
__global__ __launch_bounds__(256) void k_softgate(float* __restrict__ T2,
                                                  const float* __restrict__ clampv,
                                                  size_t bsT, size_t bsC){
  const int k = blockIdx.x, tid = threadIdx.x, b = blockIdx.y;
  float* row = &T2[(size_t)b*bsT + (size_t)k*HW];
  float vals[16];
  float mx = -3.4e38f;
  #pragma unroll
  for (int i = 0; i < 16; ++i){ vals[i] = row[tid + i*256]; mx = fmaxf(mx, vals[i]); }
  mx = wmax(mx);
  __shared__ float am[4], asm_[4];
  if ((tid & 63) == 0) am[tid>>6] = mx;
  __syncthreads();
  mx = fmaxf(fmaxf(am[0], am[1]), fmaxf(am[2], am[3]));
  float s = 0.f;
  #pragma unroll
  for (int i = 0; i < 16; ++i){ vals[i] = __expf(vals[i] - mx); s += vals[i]; }
  s = wsum(s);
  if ((tid & 63) == 0) asm_[tid>>6] = s;
  __syncthreads();
  s = asm_[0]+asm_[1]+asm_[2]+asm_[3];
  const float inv = 1.f / s;
  const float cv = clampv[(size_t)b*bsC + k];
  u16* Sg = (u16*)row;
  #pragma unroll
  for (int i = 0; i < 16; ++i){
    float sg = 1.f/(1.f + __expf(-50.f*(vals[i]*inv - cv)));
    Sg[tid + i*256] = f2bf(sg);
  }
}

extern "C" void kernel_launch(void* const* d_in, const int* in_sizes, int n_in,
                              void* d_out, int out_size, void* d_ws, size_t ws_size,
                              hipStream_t stream){
  const float* content = (const float*)d_in[0];
  const float* style   = (const float*)d_in[1];
  const float* Wf   = (const float*)d_in[2];  const float* bfv  = (const float*)d_in[3];
  const float* Wg   = (const float*)d_in[4];  const float* bg   = (const float*)d_in[5];
  const float* Wh   = (const float*)d_in[6];  const float* bh   = (const float*)d_in[7];
  const float* Wo   = (const float*)d_in[8];  const float* bout = (const float*)d_in[9];
  const float* W1   = (const float*)d_in[10]; const float* b1   = (const float*)d_in[11];
  const float* W2   = (const float*)d_in[12]; const float* b2   = (const float*)d_in[13];
  float* out = (float*)d_out;
  (void)in_sizes; (void)n_in; (void)out_size;

  char* ws = (char*)d_ws;
  size_t off = 0;
  auto alloc = [&](size_t bytes)->void*{
    void* p = (void*)(ws + off);
    off += (bytes + 255) & ~(size_t)255;
    return p;
  };
  // ---- common allocations (all modes) ----
  float2* statsC = (float2*)alloc((size_t)Bn*C*sizeof(float2));
  float2* statsS = (float2*)alloc((size_t)Bn*C*sizeof(float2));
  float*  inc    = (float*) alloc((size_t)Bn*HW*sizeof(float));
  float*  ins    = (float*) alloc((size_t)Bn*HW*sizeof(float));
  float*  clampv = (float*) alloc((size_t)Bn*HW*sizeof(float));
  u16* Wfh = (u16*)alloc((size_t)C*C*2), *Wfl = (u16*)alloc((size_t)C*C*2);
  u16* Wgh = (u16*)alloc((size_t)C*C*2), *Wgl = (u16*)alloc((size_t)C*C*2);
  u16* Whb = (u16*)alloc((size_t)C*C*2), *Wob = (u16*)alloc((size_t)C*C*2);
  u16* W1b = (u16*)alloc((size_t)HID*HW*2);
  const size_t commonEnd = off;

  const size_t TPB = (size_t)HW*C;          // per-batch transposed-slab elems (4 MB)
  const size_t XB  = (size_t)C*HW;          // per-batch fp32 input elems
  const size_t SLB = (size_t)Bn*TPB*2;      // batched bf16 slab bytes (16 MB)

  // setup (identical in all modes)
  k_stats  <<<dim3(Bn*C, 2),       256, 0, stream>>>(content, style, statsC, statsS);
  k_pixnorm<<<dim3(HW/64, Bn, 2),  256, 0, stream>>>(content, style, inc, ins);
  k_wprep  <<<dim3(HID*HW/1024, 5),256, 0, stream>>>(Wf, Wg, Wh, Wo, W1,
                                                     Wfh, Wfl, Wgh, Wgl, Whb, Wob, W1b);

  // batched prep phase: everything before the T2 chain, 7 dispatches.
  auto runPrep = [&](char* R, u16* bFqTh, u16* bFqTl, u16* bGkTh, u16* bGkTl,
                     u16* bHvb, u16* bPT){
    u16* bXcTh = (u16*)(R + 0*SLB);
    u16* bXcTl = (u16*)(R + 1*SLB);
    u16* bXsTh = (u16*)(R + 2*SLB);
    u16* bXsTl = (u16*)(R + 3*SLB);
    u16* bCrT  = (u16*)(R + 4*SLB);
    u16* bSrT  = (u16*)(R + 5*SLB);
    u16* bstS  = (u16*)(R + 6*SLB);
    float* bPpart = (float*)(R + 0*SLB);   // 16-slice partials: slots 0-1 (dead XcT*)
    float* bhmid  = (float*)(R + 1*SLB);   // hmid overlays slot 1 AFTER reduce
    k_prep2 <<<dim3(HW/64, C/64, 2*Bn), 256, 0, stream>>>(content, style, statsC, statsS, ins,
                                                          bXcTh, bXcTl, bCrT, bXsTh, bXsTl, bSrT,
                                                          bstS, XB, TPB, C, HW, TPB);
    g_conv_split2<<<dim3(C/128, HW/128, 2*Bn), 256, 0, stream>>>(
        bXcTh, bXcTl, bXsTh, bXsTl, Wfh, Wfl, Wgh, Wgl, bfv, bg,
        bFqTh, bFqTl, bGkTh, bGkTl, TPB, TPB);
    g_gemm_biasm_bf16<<<dim3(HW/128, C/128, Bn), 256, 0, stream>>>(Whb, C, bSrT, C, C, bh,
                                                                   bHvb, HW, TPB, TPB);
    // PT: split-K 16 x 256 -> 512 blocks (2/CU)
    g_gemm_partial<<<dim3(C/128, HID/128, Bn*16), 256, 0, stream>>>(W1b, HW, bstS, HW, 256,
                                                                    bPpart, C, (size_t)HID*C, 16,
                                                                    0, TPB, (size_t)16*HID*C);
    k_reduce<<<dim3(HID*C/1024, Bn), 256, 0, stream>>>(bPpart, (size_t)HID*C, 16, bPT,
                                                       (size_t)16*HID*C, (size_t)HID*C);
    g_gemm_hmid<<<dim3(HID/128, HW/128, Bn), 256, 0, stream>>>(bCrT, C, bPT, C, C, inc, b1, bhmid,
                                                               TPB, (size_t)HID*C, HW, (size_t)HW*HID);
    k_psi<<<dim3(HW, Bn), 256, 0, stream>>>(bhmid, W2, b2, clampv, (size_t)HW*HID, HW);
  };

  // ---------------- tier 1: fully batched (~378 MB) --------------------------
  {
    size_t o = commonEnd;
    auto al = [&](size_t bytes)->void*{ void* p = (void*)(ws + o); o += (bytes + 255) & ~(size_t)255; return p; };
    u16* bFqTh = (u16*)al(SLB), *bFqTl = (u16*)al(SLB);
    u16* bGkTh = (u16*)al(SLB), *bGkTl = (u16*)al(SLB);
    u16* bHvb  = (u16*)al(SLB);
    u16* bPT   = (u16*)al((size_t)Bn*HID*C*2);
    u16* bO1T  = (u16*)al(SLB);
    char* R    = (char*)al((size_t)Bn*HW*HW*4);   // 256 MB: prep slabs, then bT2
    if (o <= ws_size){
      runPrep(R, bFqTh, bFqTl, bGkTh, bGkTl, bHvb, bPT);
      float* bT2 = (float*)R;                     // overlays all dead prep slabs
      g_gemm_split_f32<<<dim3(HW/128, HW/128, Bn), 256, 0, stream>>>(bFqTh, bFqTl, C, bGkTh, bGkTl, C,
                                                                     C, bT2, HW,
                                                                     TPB, TPB, (size_t)HW*HW);
      k_softgate<<<dim3(HW, Bn), 256, 0, stream>>>(bT2, clampv, (size_t)HW*HW, HW);
      g_gemm_plain_bf16<<<dim3(C/128, HW/128, Bn), 256, 0, stream>>>((const u16*)bT2, 2*HW, bHvb, HW,
                                                                     HW, bO1T, C,
                                                                     (size_t)HW*HW*2, TPB, TPB);
      g_gemm_outconv<<<dim3(HW/128, C/128, Bn), 256, 0, stream>>>(Wob, C, bO1T, C, C, bout, content, out,
                                                                  TPB, XB, XB);
      return;
    }
  }

  // ------- tier 1.25a: 2-batch T2 chunks + split-K ogemm (2 blk/CU, ~258 MB) -
  {
    size_t o = commonEnd;
    auto al = [&](size_t bytes)->void*{ void* p = (void*)(ws + o); o += (bytes + 255) & ~(size_t)255; return p; };
    u16* bFqTh = (u16*)al(SLB), *bFqTl = (u16*)al(SLB);
    u16* bGkTh = (u16*)al(SLB), *bGkTl = (u16*)al(SLB);
    u16* bHvb  = (u16*)al(SLB);
    u16* bPT   = (u16*)al((size_t)Bn*HID*C*2);
    char* R    = (char*)al((size_t)2*HW*HW*4 + (size_t)4*HW*C*4 + (size_t)2*TPB*2); // 168 MB
    if (o <= ws_size){
      runPrep(R, bFqTh, bFqTl, bGkTh, bGkTl, bHvb, bPT);   // prep uses 112 MB of R
      float* T2s   = (float*)R;                             // 2 x 64 MB
      float* Opart = (float*)(R + (size_t)2*HW*HW*4);       // 2b x 2sl x 8 MB
      u16*   O1Ts  = (u16*)(R + (size_t)2*HW*HW*4 + (size_t)4*HW*C*4); // 2 x 4 MB
      for (int cb = 0; cb < Bn; cb += 2){
        g_gemm_split_f32<<<dim3(HW/128, HW/128, 2), 256, 0, stream>>>(
            bFqTh + (size_t)cb*TPB, bFqTl + (size_t)cb*TPB, C,
            bGkTh + (size_t)cb*TPB, bGkTl + (size_t)cb*TPB, C, C, T2s, HW,
            TPB, TPB, (size_t)HW*HW);
        k_softgate<<<dim3(HW, 2), 256, 0, stream>>>(T2s, clampv + (size_t)cb*HW,
                                                    (size_t)HW*HW, HW);
        // ogemm split-K=2 -> grid 512 (2 blk/CU latency overlap)
        g_gemm_partial<<<dim3(C/128, HW/128, 4), 256, 0, stream>>>(
            (const u16*)T2s, 2*HW, bHvb + (size_t)cb*TPB, HW, 2048,
            Opart, C, (size_t)HW*C, 2,
            (size_t)HW*HW*2, TPB, (size_t)2*HW*C);
        k_reduce<<<dim3(HW*C/1024, 2), 256, 0, stream>>>(Opart, (size_t)HW*C, 2, O1Ts,
                                                         (size_t)2*HW*C, TPB);
        g_gemm_outconv<<<dim3(HW/128, C/128, 2), 256, 0, stream>>>(
            Wob, C, O1Ts, C, C, bout, content + (size_t)cb*XB, out + (size_t)cb*XB,
            TPB, XB, XB);
      }
      return;
    }
  }

  // ------- tier 1.25b: 2-batch T2 chunks, full-K ogemm (~226 MB, R4 winner) --
  {
    size_t o = commonEnd;
    auto al = [&](size_t bytes)->void*{ void* p = (void*)(ws + o); o += (bytes + 255) & ~(size_t)255; return p; };
    u16* bFqTh = (u16*)al(SLB), *bFqTl = (u16*)al(SLB);
    u16* bGkTh = (u16*)al(SLB), *bGkTl = (u16*)al(SLB);
    u16* bHvb  = (u16*)al(SLB);
    u16* bPT   = (u16*)al((size_t)Bn*HID*C*2);
    char* R    = (char*)al((size_t)2*HW*HW*4 + (size_t)2*TPB*2 + 256); // 136 MB
    if (o <= ws_size){
      runPrep(R, bFqTh, bFqTl, bGkTh, bGkTl, bHvb, bPT);
      float* T2s  = (float*)R;                              // 2 x 64 MB
      u16*   O1Ts = (u16*)(R + (size_t)2*HW*HW*4);          // 2 x 4 MB
      for (int cb = 0; cb < Bn; cb += 2){
        g_gemm_split_f32<<<dim3(HW/128, HW/128, 2), 256, 0, stream>>>(
            bFqTh + (size_t)cb*TPB, bFqTl + (size_t)cb*TPB, C,
            bGkTh + (size_t)cb*TPB, bGkTl + (size_t)cb*TPB, C, C, T2s, HW,
            TPB, TPB, (size_t)HW*HW);
        k_softgate<<<dim3(HW, 2), 256, 0, stream>>>(T2s, clampv + (size_t)cb*HW,
                                                    (size_t)HW*HW, HW);
        g_gemm_plain_bf16<<<dim3(C/128, HW/128, 2), 256, 0, stream>>>(
            (const u16*)T2s, 2*HW, bHvb + (size_t)cb*TPB, HW, HW, O1Ts, C,
            (size_t)HW*HW*2, TPB, TPB);
        g_gemm_outconv<<<dim3(HW/128, C/128, 2), 256, 0, stream>>>(
            Wob, C, O1Ts, C, C, bout, content + (size_t)cb*XB, out + (size_t)cb*XB,
            TPB, XB, XB);
      }
      return;
    }
  }

  // ---------------- tier 1.5: batched prep + per-batch T2 chain (~199 MB) ----
  {
    size_t o = commonEnd;
    auto al = [&](size_t bytes)->void*{ void* p = (void*)(ws + o); o += (bytes + 255) & ~(size_t)255; return p; };
    u16* bFqTh = (u16*)al(SLB), *bFqTl = (u16*)al(SLB);
    u16* bGkTh = (u16*)al(SLB), *bGkTl = (u16*)al(SLB);
    u16* bHvb  = (u16*)al(SLB);
    u16* bPT   = (u16*)al((size_t)Bn*HID*C*2);
    char* R    = (char*)al(7*SLB);                // 112 MB: prep slabs, then chain scratch
    if (o <= ws_size){
      runPrep(R, bFqTh, bFqTl, bGkTh, bGkTl, bHvb, bPT);
      float* T2s   = (float*)(R + 0*SLB);         // 64 MB (slots 0-3, dead)
      float* Opart = (float*)(R + 4*SLB);         // 32 MB (slots 4-5, dead)
      u16*   O1Ts  = (u16*)  (R + 6*SLB);         //  4 MB (slot 6, dead)
      for (int b = 0; b < Bn; ++b){
        g_gemm_split_f32<<<dim3(HW/128, HW/128), 256, 0, stream>>>(
            bFqTh + (size_t)b*TPB, bFqTl + (size_t)b*TPB, C,
            bGkTh + (size_t)b*TPB, bGkTl + (size_t)b*TPB, C, C, T2s, HW, 0, 0, 0);
        k_softgate<<<dim3(HW), 256, 0, stream>>>(T2s, clampv + (size_t)b*HW, 0, 0);
        g_gemm_partial<<<dim3(C/128, HW/128, 4), 256, 0, stream>>>(
            (const u16*)T2s, 2*HW, bHvb + (size_t)b*TPB, HW, 1024,
            Opart, C, (size_t)HW*C, 4, 0, 0, 0);
        k_reduce<<<dim3(HW*C/1024), 256, 0, stream>>>(Opart, (size_t)HW*C, 4, O1Ts, 0, 0);
        g_gemm_outconv<<<dim3(HW/128, C/128), 256, 0, stream>>>(Wob, C, O1Ts, C, C, bout,
            content + (size_t)b*XB, out + (size_t)b*XB, 0, 0, 0);
      }
      return;
    }
  }

  // ---------------- fallback: proven per-batch path (~170 MB) ----------------
  off = commonEnd;
  u16* XcTh = (u16*)alloc((size_t)HW*C*2), *XcTl = (u16*)alloc((size_t)HW*C*2);
  u16* CrT  = (u16*)alloc((size_t)HW*C*2);
  u16* XsTh = (u16*)alloc((size_t)HW*C*2), *XsTl = (u16*)alloc((size_t)HW*C*2);
  u16* SrT  = (u16*)alloc((size_t)HW*C*2);
  u16* stS  = (u16*)alloc((size_t)C*HW*2);
  u16* FqTh = (u16*)alloc((size_t)HW*C*2), *FqTl = (u16*)alloc((size_t)HW*C*2);
  u16* GkTh = (u16*)alloc((size_t)HW*C*2), *GkTl = (u16*)alloc((size_t)HW*C*2);
  u16* Hvb  = (u16*)alloc((size_t)C*HW*2);
  u16* O1T  = (u16*)alloc((size_t)HW*C*2);
  u16* PT   = (u16*)alloc((size_t)HID*C*2);
  float* hmid  = (float*)alloc((size_t)HW*HID*sizeof(float));
  float* Ppart = (float*)alloc((size_t)16*HID*C*sizeof(float));   // 8 MB
  float* Opart = (float*)alloc((size_t)4*HW*C*sizeof(float));     // 32 MB
  float* T2    = (float*)alloc((size_t)HW*HW*sizeof(float));      // 64 MB

  for (int b = 0; b < Bn; ++b){
    const float* cb = content + (size_t)b*C*HW;
    const float* sb = style   + (size_t)b*C*HW;
    const float* incb = inc + (size_t)b*HW;
    const float* insb = ins + (size_t)b*HW;
    float* clb = clampv + (size_t)b*HW;

    k_prep2 <<<dim3(HW/64, C/64, 2), 256, 0, stream>>>(cb, sb, statsC + (size_t)b*C, statsS + (size_t)b*C,
                                                       insb, XcTh, XcTl, CrT, XsTh, XsTl, SrT,
                                                       stS, 0, 0, 0, 0, 0);
    g_conv_split2<<<dim3(C/128, HW/128, 2), 256, 0, stream>>>(
        XcTh, XcTl, XsTh, XsTl, Wfh, Wfl, Wgh, Wgl, bfv, bg,
        FqTh, FqTl, GkTh, GkTl, 0, 0);
    g_gemm_biasm_bf16<<<dim3(HW/128, C/128), 256, 0, stream>>>(Whb, C, SrT, C, C, bh, Hvb, HW, 0, 0);
    g_gemm_partial<<<dim3(C/128, HID/128, 16), 256, 0, stream>>>(W1b, HW, stS, HW, 256,
                                                                 Ppart, C, (size_t)HID*C, 16, 0, 0, 0);
    k_reduce<<<dim3(HID*C/1024), 256, 0, stream>>>(Ppart, (size_t)HID*C, 16, PT, 0, 0);
    g_gemm_hmid<<<dim3(HID/128, HW/128), 256, 0, stream>>>(CrT, C, PT, C, C, incb, b1, hmid, 0, 0, 0, 0);
    k_psi<<<dim3(HW), 256, 0, stream>>>(hmid, W2, b2, clb, 0, 0);
    g_gemm_split_f32<<<dim3(HW/128, HW/128), 256, 0, stream>>>(FqTh, FqTl, C, GkTh, GkTl, C, C, T2, HW, 0, 0, 0);
    k_softgate<<<dim3(HW), 256, 0, stream>>>(T2, clb, 0, 0);
    g_gemm_partial<<<dim3(C/128, HW/128, 4), 256, 0, stream>>>((const u16*)T2, 2*HW, Hvb, HW, 1024,
                                                               Opart, C, (size_t)HW*C, 4, 0, 0, 0);
    k_reduce<<<dim3(HW*C/1024), 256, 0, stream>>>(Opart, (size_t)HW*C, 4, O1T, 0, 0);
    g_gemm_outconv<<<dim3(HW/128, C/128), 256, 0, stream>>>(Wob, C, O1T, C, C, bout, cb,
                                                            out + (size_t)b*C*HW, 0, 0, 0);
  }
}